// Round 8
// baseline (117.055 us; speedup 1.0000x reference)
//
#include <hip/hip_runtime.h>

// ChebyshevAdditiveAngularMargin — HBM-bound elementwise op.
//   cosine = clip(outputs, -1+1e-7, 1-1e-7)
//   phi    = clenshaw(cosine, coeffs)            (Chebyshev, degree 30)
//   phi    = cosine > TH ? phi : cosine - MM
//   out    = 30 * (targets*phi + (1-targets)*cosine)   (targets one-hot)
//
// Traffic: outputs 256MB (HBM, NT) + targets 256MB (L3-resident, cached) +
// write 256MB (HBM, NT). Ladder: R1 162 -> R4 one-shot 4x/thread 145 ->
// R7 +NT on streaming pair 115. R8: force real MLP — R7's VGPR=20 proves
// the compiler serialized the load batch (~2 loads in flight vs 8 coded).
// kPerThread=8, o/t pairs adjacent, sched_barrier(0) pins all 16 loads
// before any compute; NT loads take full HBM latency so depth matters.

namespace {

typedef float f32x4 __attribute__((ext_vector_type(4)));

constexpr float kClipLo = -0.9999999f;   // -1 + 1e-7 rounded to f32
constexpr float kClipHi =  0.9999999f;   //  1 - 1e-7 rounded to f32
constexpr float kTH     = -0.98006657784124163f;  // cos(pi - 0.2)
constexpr float kMM     =  0.039733866159012243f; // sin(pi - 0.2) * 0.2
constexpr float kSCALE  = 30.0f;
constexpr int   kDegree = 30;            // 31 coefficients
constexpr int   kPerThread = 8;          // float4s per thread per array

__device__ __forceinline__ float clenshaw_phi(float x, const float* __restrict__ coeffs) {
    // b_k = c_k + 2x*b_{k+1} - b_{k+2}, k = DEGREE..0;  f(x) = b_0 - x*b_1
    const float x2 = 2.0f * x;
    float b1 = 0.0f, b2 = 0.0f;
#pragma unroll
    for (int k = kDegree; k >= 0; --k) {
        float b = coeffs[k] + x2 * b1 - b2;
        b2 = b1;
        b1 = b;
    }
    return b1 - b2 * x;
}

__device__ __forceinline__ f32x4 process4(f32x4 o, f32x4 t,
                                          const float* __restrict__ coeffs) {
    f32x4 r;
#pragma unroll
    for (int j = 0; j < 4; ++j) {
        const float x = fminf(fmaxf(o[j], kClipLo), kClipHi);
        float rv = x;  // targets == 0 path: out = cosine
        if (t[j] != 0.0f) {
            // rare path: ~1 element per 8192
            const float phi = (x > kTH) ? clenshaw_phi(x, coeffs) : (x - kMM);
            rv = t[j] * phi + (1.0f - t[j]) * x;
        }
        r[j] = kSCALE * rv;
    }
    return r;
}

// One shot per thread: kPerThread coalesced float4 per array, stride-256
// within the block. ALL loads issued before any compute (sched_barrier
// stops the register allocator from re-serializing them); o/t pairs are
// adjacent so process4(u) waits only on incremental vmcnt, with the rest
// of the 16 loads still in flight. outputs/dst nontemporal, targets cached.
__global__ __launch_bounds__(256) void cheb_aam_kernel(
    const f32x4* __restrict__ outputs4,
    const f32x4* __restrict__ targets4,
    const float* __restrict__ coeffs,
    f32x4*       __restrict__ dst4,
    int n4) {
    const int base = blockIdx.x * (256 * kPerThread) + threadIdx.x;

    if (base + 256 * (kPerThread - 1) < n4) {  // uniform fast path
        f32x4 o[kPerThread], t[kPerThread];
#pragma unroll
        for (int u = 0; u < kPerThread; ++u) {
            o[u] = __builtin_nontemporal_load(&outputs4[base + 256 * u]);
            t[u] = targets4[base + 256 * u];
        }
        __builtin_amdgcn_sched_barrier(0);   // pin: loads above, compute below
#pragma unroll
        for (int u = 0; u < kPerThread; ++u) {
            f32x4 r = process4(o[u], t[u], coeffs);
            __builtin_nontemporal_store(r, &dst4[base + 256 * u]);
        }
    } else {  // tail block (not taken for 8192x8192)
#pragma unroll
        for (int u = 0; u < kPerThread; ++u) {
            const int i = base + 256 * u;
            if (i < n4) {
                f32x4 r = process4(__builtin_nontemporal_load(&outputs4[i]),
                                   targets4[i], coeffs);
                __builtin_nontemporal_store(r, &dst4[i]);
            }
        }
    }
}

}  // namespace

extern "C" void kernel_launch(void* const* d_in, const int* in_sizes, int n_in,
                              void* d_out, int out_size, void* d_ws, size_t ws_size,
                              hipStream_t stream) {
    const float* outputs = (const float*)d_in[0];
    const float* targets = (const float*)d_in[1];
    const float* coeffs  = (const float*)d_in[2];
    float* dst = (float*)d_out;

    const int n  = out_size;       // 8192*8192, divisible by 4
    const int n4 = n / 4;

    const int block = 256;
    const int perBlock = block * kPerThread;           // 2048 float4 / block
    const int grid = (n4 + perBlock - 1) / perBlock;   // 8192 for 8192^2

    cheb_aam_kernel<<<grid, block, 0, stream>>>(
        (const f32x4*)outputs, (const f32x4*)targets, coeffs,
        (f32x4*)dst, n4);
}